// Round 17
// baseline (275.894 us; speedup 1.0000x reference)
//
#include <hip/hip_runtime.h>
#include <hip/hip_fp16.h>

#define NN 50000
#define NER 800000
#define NE 850000
#define MAXN 0.996f
#define MINNRM 1e-15f
#define SCAN_B 256
#define NBLK ((NN + SCAN_B - 1) / SCAN_B)   // 196
#define HB ((NE + 255) / 256)               // 3321
#define G0B ((NN + 63) / 64)                // 782

typedef _Float16 h2 __attribute__((ext_vector_type(2)));
typedef _Float16 h8 __attribute__((ext_vector_type(8)));
typedef float f32x4 __attribute__((ext_vector_type(4)));
union UB4 { uint4 u; h2 h[4]; };

__device__ __forceinline__ h2 f2h2(float a, float b){ h2 r; r.x=(_Float16)a; r.y=(_Float16)b; return r; }
__device__ __forceinline__ h2 splat(float a){ h2 r; r.x=(_Float16)a; r.y=(_Float16)a; return r; }

__device__ __forceinline__ float gsum16(float v){
  v += __shfl_xor(v, 1, 64); v += __shfl_xor(v, 2, 64);
  v += __shfl_xor(v, 4, 64); v += __shfl_xor(v, 8, 64);
  return v;
}
__device__ __forceinline__ float gmax16(float v){
  v = fmaxf(v, __shfl_xor(v, 1, 64)); v = fmaxf(v, __shfl_xor(v, 2, 64));
  v = fmaxf(v, __shfl_xor(v, 4, 64)); v = fmaxf(v, __shfl_xor(v, 8, 64));
  return v;
}
__device__ __forceinline__ float artanh_c(float t){
  t = fminf(t, 1.0f - 1e-7f);
  return 0.5f * (log1pf(t) - log1pf(-t));
}
__device__ __forceinline__ float lrelu(float t, float s){ return t >= 0.f ? t : s * t; }

__device__ void bias_blk(const float* b, const float* ai, const float* aj, int L, int HS, float* hbx){
  __shared__ float red[256];
  __shared__ float hai[4], haj[4];
  int t = threadIdx.x;
  float v = (t < L) ? b[t] : 0.f;
  red[t] = v * v; __syncthreads();
  for (int s = 128; s; s >>= 1){ if (t < s) red[t] += red[t + s]; __syncthreads(); }
  float n  = fmaxf(sqrtf(red[0]), MINNRM);
  float un = tanhf(n);
  float nn = un;
  float f  = un / n;
  if (un > MAXN){ f = MAXN / n; nn = MAXN; }
  float hb = v * f;
  if (t < L) hbx[t] = hb;
  if (t < 4){ hai[t] = 0.f; haj[t] = 0.f; }
  __syncthreads();
  if (t < L){
    int h = t / HS;
    atomicAdd(&hai[h], hb * ai[t]);
    atomicAdd(&haj[h], hb * aj[t]);
  }
  __syncthreads();
  if (t == 0) hbx[L] = nn * nn;
  if (t < 4){ hbx[L + 1 + t] = hai[t]; hbx[L + 5 + t] = haj[t]; }
}

__device__ __forceinline__ void wconv(const float* in, __half* outp, int Nr, int Kc, int i){
  int tot = Nr * (Kc >> 1);
  if (i >= tot) return;
  int kp = i / Nr, n = i % Nr;
  __half2 v;
  v.x = __float2half(in[(size_t)n * Kc + 2 * kp]);
  v.y = __float2half(in[(size_t)n * Kc + 2 * kp + 1]);
  ((__half2*)outp)[i] = v;
}

// ---- fused prep: biases + weight converts + edge histogram (captures rank) ----
__global__ __launch_bounds__(256) void kprep(
    const float* __restrict__ b1, const float* __restrict__ ai1, const float* __restrict__ aj1, float* __restrict__ hbx1,
    const float* __restrict__ b2, const float* __restrict__ ai2, const float* __restrict__ aj2, float* __restrict__ hbx2,
    const float* __restrict__ Wl, __half* __restrict__ Wlh,
    const float* __restrict__ W1, __half* __restrict__ W1h,
    const float* __restrict__ W2, __half* __restrict__ W2m,
    const int* __restrict__ ei, int* __restrict__ cnt, int* __restrict__ rank){
  int bid = blockIdx.x, tid = threadIdx.x;
  if (bid == 0){ bias_blk(b1, ai1, aj1, 128, 32, hbx1); return; }
  if (bid == 1){ bias_blk(b2, ai2, aj2, 256, 64, hbx2); return; }
  if (bid < 18){ wconv(Wl, Wlh, 64, 128, (bid - 2) * 256 + tid); return; }
  if (bid < 34){ wconv(W1, W1h, 128, 64, (bid - 18) * 256 + tid); return; }
  if (bid < 162){  // W2 plain fp16 cast, row-major [256][128]
    int i = (bid - 34) * 256 + tid;
    if (i < 256 * 128) W2m[i] = __float2half(W2[i]);
    return;
  }
  int e = (bid - 162) * 256 + tid;
  if (e >= NE) return;
  int s = (e < NER) ? ei[e] : (e - NER);
  rank[e] = atomicAdd(&cnt[s], 1);
}

// ---- k_g0 body ----
__device__ void kg0_body(int bid, const float* __restrict__ x, const __half* __restrict__ Wlh,
                         const float* __restrict__ bl, __half* __restrict__ h0h,
                         float* __restrict__ xn0){
  __shared__ __align__(16) h2 As2[16][68];
  __shared__ __align__(16) h2 Bs2[16][68];
  __shared__ float red[64][2];
  int tid = threadIdx.x, wave = tid >> 6, lane = tid & 63;
  int wr = wave >> 1, wc = wave & 1, lr = lane >> 3, lc = lane & 7;
  int row0 = bid * 64;
  int r0 = wr * 32 + lr * 4, c0 = wc * 32 + lc * 4;
  float acc[4][4] = {};
  int am = tid >> 2, aq = tid & 3;
  int bkp = tid >> 4, bn4 = (tid & 15) * 4;
  const uint* Wlu = (const uint*)Wlh;
  float4 ra0, ra1; uint4 rb;
  {
    int row = row0 + am;
    ra0 = make_float4(0.f,0.f,0.f,0.f); ra1 = ra0;
    if (row < NN){
      ra0 = *(const float4*)(x + (size_t)row * 128 + aq * 8);
      ra1 = *(const float4*)(x + (size_t)row * 128 + aq * 8 + 4);
    }
    rb = *(const uint4*)(Wlu + (size_t)bkp * 64 + bn4);
  }
  for (int ks = 0; ks < 4; ks++){
    __syncthreads();
    As2[aq*4+0][am] = f2h2(ra0.x, ra0.y);
    As2[aq*4+1][am] = f2h2(ra0.z, ra0.w);
    As2[aq*4+2][am] = f2h2(ra1.x, ra1.y);
    As2[aq*4+3][am] = f2h2(ra1.z, ra1.w);
    *(uint4*)&Bs2[bkp][bn4] = rb;
    __syncthreads();
    if (ks < 3){
      int k0 = (ks + 1) * 32;
      int row = row0 + am;
      ra0 = make_float4(0.f,0.f,0.f,0.f); ra1 = ra0;
      if (row < NN){
        ra0 = *(const float4*)(x + (size_t)row * 128 + k0 + aq * 8);
        ra1 = *(const float4*)(x + (size_t)row * 128 + k0 + aq * 8 + 4);
      }
      rb = *(const uint4*)(Wlu + (size_t)((ks + 1) * 16 + bkp) * 64 + bn4);
    }
#pragma unroll
    for (int kp = 0; kp < 16; kp++){
      UB4 av, bv;
      av.u = *(const uint4*)&As2[kp][r0];
      bv.u = *(const uint4*)&Bs2[kp][c0];
#pragma unroll
      for (int i = 0; i < 4; i++)
#pragma unroll
        for (int j = 0; j < 4; j++)
          acc[i][j] = __builtin_amdgcn_fdot2(av.h[i], bv.h[j], acc[i][j], false);
    }
  }
  float bb[4];
  *(float4*)&bb[0] = *(const float4*)(bl + c0);
#pragma unroll
  for (int i = 0; i < 4; i++){
    float rs = 0.f;
#pragma unroll
    for (int j = 0; j < 4; j++){ acc[i][j] += bb[j]; rs = fmaf(acc[i][j], acc[i][j], rs); }
    rs += __shfl_xor(rs, 1, 64);
    rs += __shfl_xor(rs, 2, 64);
    rs += __shfl_xor(rs, 4, 64);
    if (lc == 0) red[r0 + i][wc] = rs;
  }
  __syncthreads();
#pragma unroll
  for (int i = 0; i < 4; i++){
    int row = row0 + r0 + i;
    if (row >= NN) continue;
    float rs = red[r0 + i][0] + red[r0 + i][1];
    float n  = fmaxf(sqrtf(rs), MINNRM);
    float un = tanhf(n);
    float f, nm;
    if (un > MAXN){ f = MAXN / n; nm = MAXN; } else { f = un / n; nm = un; }
    union { uint2 u; __half2 h[2]; } st;
    st.h[0] = __floats2half2_rn(acc[i][0] * f, acc[i][1] * f);
    st.h[1] = __floats2half2_rn(acc[i][2] * f, acc[i][3] * f);
    *(uint2*)(h0h + (size_t)row * 64 + c0) = st.u;
    if (wc == 0 && lc == 0) xn0[row] = nm;
  }
}

// ---- merged: kscan1 (blocks<NBLK) + k_g0 (rest) ----
__global__ __launch_bounds__(256) void kB(const int* __restrict__ cnt,
                                          int* __restrict__ part, int* __restrict__ bsum,
                                          const float* __restrict__ x, const __half* __restrict__ Wlh,
                                          const float* __restrict__ bl, __half* __restrict__ h0h,
                                          float* __restrict__ xn0){
  int bid = blockIdx.x;
  if (bid < NBLK){
    __shared__ int sh[SCAN_B];
    int t = threadIdx.x;
    int i = bid * SCAN_B + t;
    int v = (i < NN) ? cnt[i] : 0;
    sh[t] = v; __syncthreads();
    for (int d = 1; d < SCAN_B; d <<= 1){
      int u = (t >= d) ? sh[t - d] : 0;
      __syncthreads();
      sh[t] += u;
      __syncthreads();
    }
    if (i < NN) part[i] = sh[t];
    if (t == SCAN_B - 1) bsum[bid] = sh[t];
    return;
  }
  kg0_body(bid - NBLK, x, Wlh, bl, h0h, xn0);
}

__global__ __launch_bounds__(256) void kscan2(int* __restrict__ bsum){
  __shared__ int sh[256];
  int t = threadIdx.x;
  int v = (t < NBLK) ? bsum[t] : 0;
  sh[t] = v; __syncthreads();
  for (int d = 1; d < 256; d <<= 1){
    int u = (t >= d) ? sh[t - d] : 0;
    __syncthreads();
    sh[t] += u;
    __syncthreads();
  }
  if (t < NBLK) bsum[t] = sh[t];
}

__global__ __launch_bounds__(SCAN_B) void kscan3(const int* __restrict__ part, const int* __restrict__ bsum,
                                                 const int* __restrict__ cnt, int* __restrict__ rowptr){
  int t = threadIdx.x;
  int i = blockIdx.x * SCAN_B + t;
  if (i < NN){
    int base = blockIdx.x ? bsum[blockIdx.x - 1] : 0;
    rowptr[i] = base + part[i] - cnt[i];
  }
  if (i == 0) rowptr[NN] = bsum[NBLK - 1];
}

// ---- kg1f body ----
__device__ void kg1f_body(int bid, const __half* __restrict__ Ah, const __half* __restrict__ W1h,
    const float* __restrict__ xn0, const float* __restrict__ hbx,
    const float* __restrict__ ai, const float* __restrict__ aj,
    __half* __restrict__ ht1, float* __restrict__ s1i, float* __restrict__ s1j){
  __shared__ __align__(16) h2 As2[16][68];
  __shared__ __align__(16) h2 Bs2[16][132];
  __shared__ float red[64][12];
  int tid = threadIdx.x, wave = tid >> 6, lane = tid & 63;
  int wr = wave >> 1, wc = wave & 1, lr = lane >> 3, lc = lane & 7;
  int row0 = bid * 64;
  int r0 = wr * 32 + lr * 4, c0 = wc * 64 + lc * 8;
  float acc[4][8] = {};
  const uint* Au = (const uint*)Ah;
  const uint* Bu = (const uint*)W1h;
  int akp = tid & 15, am0 = (tid >> 4) * 4;
  int bkp = tid >> 4, bcol = (tid & 15) * 4;
  uint ua0, ua1, ua2, ua3; uint4 ub0, ub1;
  {
    int r;
    ua0 = ua1 = ua2 = ua3 = 0u;
    r = row0 + am0 + 0; if (r < NN) ua0 = Au[(size_t)r * 32 + akp];
    r = row0 + am0 + 1; if (r < NN) ua1 = Au[(size_t)r * 32 + akp];
    r = row0 + am0 + 2; if (r < NN) ua2 = Au[(size_t)r * 32 + akp];
    r = row0 + am0 + 3; if (r < NN) ua3 = Au[(size_t)r * 32 + akp];
    ub0 = *(const uint4*)(Bu + (size_t)bkp * 128 + bcol);
    ub1 = *(const uint4*)(Bu + (size_t)bkp * 128 + bcol + 64);
  }
  for (int ks = 0; ks < 2; ks++){
    __syncthreads();
    { uint4 av4; av4.x = ua0; av4.y = ua1; av4.z = ua2; av4.w = ua3;
      *(uint4*)&As2[akp][am0] = av4; }
    *(uint4*)&Bs2[bkp][bcol]      = ub0;
    *(uint4*)&Bs2[bkp][bcol + 64] = ub1;
    __syncthreads();
    if (ks < 1){
      int r;
      ua0 = ua1 = ua2 = ua3 = 0u;
      r = row0 + am0 + 0; if (r < NN) ua0 = Au[(size_t)r * 32 + 16 + akp];
      r = row0 + am0 + 1; if (r < NN) ua1 = Au[(size_t)r * 32 + 16 + akp];
      r = row0 + am0 + 2; if (r < NN) ua2 = Au[(size_t)r * 32 + 16 + akp];
      r = row0 + am0 + 3; if (r < NN) ua3 = Au[(size_t)r * 32 + 16 + akp];
      ub0 = *(const uint4*)(Bu + (size_t)(16 + bkp) * 128 + bcol);
      ub1 = *(const uint4*)(Bu + (size_t)(16 + bkp) * 128 + bcol + 64);
    }
#pragma unroll
    for (int kp = 0; kp < 16; kp++){
      UB4 av, bv0, bv1;
      av.u  = *(const uint4*)&As2[kp][r0];
      bv0.u = *(const uint4*)&Bs2[kp][c0];
      bv1.u = *(const uint4*)&Bs2[kp][c0 + 4];
#pragma unroll
      for (int i = 0; i < 4; i++){
#pragma unroll
        for (int j = 0; j < 4; j++)
          acc[i][j] = __builtin_amdgcn_fdot2(av.h[i], bv0.h[j], acc[i][j], false);
#pragma unroll
        for (int j = 4; j < 8; j++)
          acc[i][j] = __builtin_amdgcn_fdot2(av.h[i], bv1.h[j - 4], acc[i][j], false);
      }
    }
  }
  float hbv[8], aiv[8], ajv[8];
  *(float4*)&hbv[0] = *(const float4*)(hbx + c0); *(float4*)&hbv[4] = *(const float4*)(hbx + c0 + 4);
  *(float4*)&aiv[0] = *(const float4*)(ai + c0);  *(float4*)&aiv[4] = *(const float4*)(ai + c0 + 4);
  *(float4*)&ajv[0] = *(const float4*)(aj + c0);  *(float4*)&ajv[4] = *(const float4*)(aj + c0 + 4);
  float b2 = hbx[128];
  int head = wc * 2 + (lc >> 2);
#pragma unroll
  for (int i = 0; i < 4; i++){
    float p1=0.f, p2=0.f, pai=0.f, paj=0.f;
#pragma unroll
    for (int j = 0; j < 8; j++){
      float a = acc[i][j];
      p1 += a*a; p2 += a*hbv[j]; pai += a*aiv[j]; paj += a*ajv[j];
    }
    p1 += __shfl_xor(p1,1,64); p1 += __shfl_xor(p1,2,64); p1 += __shfl_xor(p1,4,64);
    p2 += __shfl_xor(p2,1,64); p2 += __shfl_xor(p2,2,64); p2 += __shfl_xor(p2,4,64);
    pai += __shfl_xor(pai,1,64); pai += __shfl_xor(pai,2,64);
    paj += __shfl_xor(paj,1,64); paj += __shfl_xor(paj,2,64);
    int rloc = r0 + i;
    if (lc == 0){ red[rloc][wc] = p1; red[rloc][2+wc] = p2; }
    if ((lc & 3) == 0){ red[rloc][4+head] = pai; red[rloc][8+head] = paj; }
  }
  __syncthreads();
#pragma unroll
  for (int i = 0; i < 4; i++){
    int row = row0 + r0 + i;
    if (row >= NN) continue;
    int rloc = r0 + i;
    float S1 = red[rloc][0] + red[rloc][1];
    float S2 = red[rloc][2] + red[rloc][3];
    float xn = fmaxf(xn0[row], MINNRM);
    float r_art = artanh_c(xn);
    float mxn = fmaxf(sqrtf(S1), MINNRM);
    float tn = tanhf(mxn / xn * r_art);
    float sc_ = tn / mxn;
    float rn = tn;
    if (rn > MAXN){ sc_ *= MAXN / rn; rn = MAXN; }
    float a2r = rn * rn;
    float ab = sc_ * S2;
    float co1 = 1.f + 2.f*ab + b2, co2 = 1.f - a2r;
    float den = fmaxf(1.f + 2.f*ab + a2r*b2, MINNRM);
    float P = co1 * sc_ / den, Q = co2 / den;
    float hn2 = P*P*S1 + 2.f*P*Q*S2 + Q*Q*b2;
    float hn = fmaxf(sqrtf(hn2), MINNRM);
    if (hn > MAXN){ float R = MAXN / hn; P *= R; Q *= R; hn = MAXN; }
    float lf = artanh_c(hn) / hn;
    union { __half h[8]; float4 f4; } ho;
#pragma unroll
    for (int j = 0; j < 8; j++) ho.h[j] = __float2half(lf * (P * acc[i][j] + Q * hbv[j]));
    *(float4*)(ht1 + (size_t)row * 128 + c0) = ho.f4;
    if (lc == 0){
      float pi0 = lf * (P * red[rloc][4+2*wc]   + Q * hbx[129+2*wc]);
      float pi1 = lf * (P * red[rloc][4+2*wc+1] + Q * hbx[129+2*wc+1]);
      float pj0 = lf * (P * red[rloc][8+2*wc]   + Q * hbx[133+2*wc]);
      float pj1 = lf * (P * red[rloc][8+2*wc+1] + Q * hbx[133+2*wc+1]);
      s1i[row*4+2*wc] = pi0; s1i[row*4+2*wc+1] = pi1;
      s1j[row*4+2*wc] = pj0; s1j[row*4+2*wc+1] = pj1;
    }
  }
}

// ---- merged: kg1f (blocks<G0B) + rank-based fill (rest) ----
__global__ __launch_bounds__(256) void kE(const int* __restrict__ ei, const int* __restrict__ rowptr,
    const int* __restrict__ rank, int* __restrict__ col,
    const __half* __restrict__ Ah, const __half* __restrict__ W1h,
    const float* __restrict__ xn0, const float* __restrict__ hbx,
    const float* __restrict__ ai, const float* __restrict__ aj,
    __half* __restrict__ ht1, float* __restrict__ s1i, float* __restrict__ s1j){
  int bid = blockIdx.x;
  if (bid >= G0B){
    int e = (bid - G0B) * 256 + threadIdx.x;
    if (e >= NE) return;
    int s, d;
    if (e < NER){ s = ei[e]; d = ei[NER + e]; }
    else { s = e - NER; d = s; }
    col[rowptr[s] + rank[e]] = d;
    return;
  }
  kg1f_body(bid, Ah, W1h, xn0, hbx, ai, aj, ht1, s1i, s1j);
}

// ---- kg2m: hyp_linear layer2 via MFMA 16x16x32 f16. block=32 rows x 256 cols ----
__global__ __launch_bounds__(256) void kg2m(const __half* __restrict__ Ah, const __half* __restrict__ W2m,
    const float* __restrict__ xn1, const float* __restrict__ hbx,
    const float* __restrict__ ai, const float* __restrict__ aj,
    __half* __restrict__ ht2, float* __restrict__ s2i, float* __restrict__ s2j){
  __shared__ float red[32][16];
  int tid = threadIdx.x, w = tid >> 6, lane = tid & 63;
  int lm = lane & 15, lg = lane >> 4;
  int row0 = blockIdx.x * 32;
  const _Float16* Af = (const _Float16*)Ah;
  const _Float16* Bf = (const _Float16*)W2m;
  // A fragments: row = lane&15, k = (lane>>4)*8 + j
  const _Float16* A0 = Af + (size_t)(row0 + lm) * 128 + lg * 8;
  h8 a00 = *(const h8*)(A0);
  h8 a01 = *(const h8*)(A0 + 32);
  h8 a02 = *(const h8*)(A0 + 64);
  h8 a03 = *(const h8*)(A0 + 96);
  h8 a10, a11, a12, a13;
  h8 zf = {};
  bool v1 = (row0 + 31) < NN;   // NN%32==16 so last block's rt=1 half is uniformly invalid
  if (v1){
    const _Float16* A1 = Af + (size_t)(row0 + 16 + lm) * 128 + lg * 8;
    a10 = *(const h8*)(A1);
    a11 = *(const h8*)(A1 + 32);
    a12 = *(const h8*)(A1 + 64);
    a13 = *(const h8*)(A1 + 96);
  } else { a10 = zf; a11 = zf; a12 = zf; a13 = zf; }
  f32x4 c00 = {0.f,0.f,0.f,0.f}, c01 = c00, c02 = c00, c03 = c00;
  f32x4 c10 = c00, c11 = c00, c12 = c00, c13 = c00;
#define DO_CT(CT, C0, C1) { \
    const _Float16* Bp = Bf + (size_t)(w * 64 + (CT) * 16 + lm) * 128 + lg * 8; \
    h8 b0 = *(const h8*)(Bp); \
    h8 b1 = *(const h8*)(Bp + 32); \
    h8 b2v = *(const h8*)(Bp + 64); \
    h8 b3 = *(const h8*)(Bp + 96); \
    C0 = __builtin_amdgcn_mfma_f32_16x16x32_f16(a00, b0,  C0, 0, 0, 0); \
    C0 = __builtin_amdgcn_mfma_f32_16x16x32_f16(a01, b1,  C0, 0, 0, 0); \
    C0 = __builtin_amdgcn_mfma_f32_16x16x32_f16(a02, b2v, C0, 0, 0, 0); \
    C0 = __builtin_amdgcn_mfma_f32_16x16x32_f16(a03, b3,  C0, 0, 0, 0); \
    C1 = __builtin_amdgcn_mfma_f32_16x16x32_f16(a10, b0,  C1, 0, 0, 0); \
    C1 = __builtin_amdgcn_mfma_f32_16x16x32_f16(a11, b1,  C1, 0, 0, 0); \
    C1 = __builtin_amdgcn_mfma_f32_16x16x32_f16(a12, b2v, C1, 0, 0, 0); \
    C1 = __builtin_amdgcn_mfma_f32_16x16x32_f16(a13, b3,  C1, 0, 0, 0); }
  DO_CT(0, c00, c10)
  DO_CT(1, c01, c11)
  DO_CT(2, c02, c12)
  DO_CT(3, c03, c13)
#undef DO_CT
  // per-lane column constants (col = w*64 + ct*16 + lm)
  int cb = w * 64 + lm;
  float hb0 = hbx[cb], hb1 = hbx[cb+16], hb2c = hbx[cb+32], hb3c = hbx[cb+48];
  float ai0 = ai[cb], ai1v = ai[cb+16], ai2c = ai[cb+32], ai3 = ai[cb+48];
  float aj0 = aj[cb], aj1v = aj[cb+16], aj2c = aj[cb+32], aj3 = aj[cb+48];
  float b2s = hbx[256];
  // per-(rt,ri) row partials over this wave's 64 cols
#pragma unroll
  for (int rt = 0; rt < 2; rt++){
#pragma unroll
    for (int ri = 0; ri < 4; ri++){
      float v0 = rt ? c10[ri] : c00[ri];
      float v1v = rt ? c11[ri] : c01[ri];
      float v2v = rt ? c12[ri] : c02[ri];
      float v3v = rt ? c13[ri] : c03[ri];
      float p1 = v0*v0 + v1v*v1v + v2v*v2v + v3v*v3v;
      float p2 = v0*hb0 + v1v*hb1 + v2v*hb2c + v3v*hb3c;
      float pa = v0*ai0 + v1v*ai1v + v2v*ai2c + v3v*ai3;
      float pj = v0*aj0 + v1v*aj1v + v2v*aj2c + v3v*aj3;
      p1 = gsum16(p1); p2 = gsum16(p2); pa = gsum16(pa); pj = gsum16(pj);
      if (lm == 0){
        int rloc = rt*16 + lg*4 + ri;
        red[rloc][w] = p1; red[rloc][4+w] = p2; red[rloc][8+w] = pa; red[rloc][12+w] = pj;
      }
    }
  }
  __syncthreads();
#pragma unroll
  for (int rt = 0; rt < 2; rt++){
#pragma unroll
    for (int ri = 0; ri < 4; ri++){
      int row = row0 + rt*16 + lg*4 + ri;
      if (row >= NN) continue;
      int rloc = rt*16 + lg*4 + ri;
      float S1 = red[rloc][0]+red[rloc][1]+red[rloc][2]+red[rloc][3];
      float S2 = red[rloc][4]+red[rloc][5]+red[rloc][6]+red[rloc][7];
      float xn = fmaxf(xn1[row], MINNRM);
      float r_art = artanh_c(xn);
      float mxn = fmaxf(sqrtf(S1), MINNRM);
      float tn = tanhf(mxn / xn * r_art);
      float sc_ = tn / mxn;
      float rn = tn;
      if (rn > MAXN){ sc_ *= MAXN / rn; rn = MAXN; }
      float a2r = rn * rn;
      float ab = sc_ * S2;
      float co1 = 1.f + 2.f*ab + b2s, co2 = 1.f - a2r;
      float den = fmaxf(1.f + 2.f*ab + a2r*b2s, MINNRM);
      float P = co1 * sc_ / den, Q = co2 / den;
      float hn2 = P*P*S1 + 2.f*P*Q*S2 + Q*Q*b2s;
      float hn = fmaxf(sqrtf(hn2), MINNRM);
      if (hn > MAXN){ float R = MAXN / hn; P *= R; Q *= R; hn = MAXN; }
      float lf = artanh_c(hn) / hn;
      float v0 = rt ? c10[ri] : c00[ri];
      float v1v = rt ? c11[ri] : c01[ri];
      float v2v = rt ? c12[ri] : c02[ri];
      float v3v = rt ? c13[ri] : c03[ri];
      __half* hp = ht2 + (size_t)row * 256 + w * 64 + lm;
      hp[0]  = __float2half(lf * (P * v0  + Q * hb0));
      hp[16] = __float2half(lf * (P * v1v + Q * hb1));
      hp[32] = __float2half(lf * (P * v2v + Q * hb2c));
      hp[48] = __float2half(lf * (P * v3v + Q * hb3c));
      if (lm == 0){
        float piv = lf * (P * red[rloc][8+w]  + Q * hbx[257+w]);
        float pjv = lf * (P * red[rloc][12+w] + Q * hbx[261+w]);
        s2i[row*4+w] = piv; s2j[row*4+w] = pjv;
      }
    }
  }
}

// ---- agg1: 16-lane group/node; superchunk; packed-fp16 gather ----
__global__ __launch_bounds__(256) void k_agg1(const int* __restrict__ rowptr, const int* __restrict__ col,
    const __half* __restrict__ ht1, const float* __restrict__ s1i, const float* __restrict__ s1j,
    __half* __restrict__ hacth, float* __restrict__ xn1){
  __shared__ int    sd[4][4][68];
  __shared__ float4 swl[4][4][66];
  int tid = threadIdx.x, wave = tid >> 6, lane = tid & 63;
  int g = lane >> 4, l = lane & 15, hh = l >> 2;
  int n = blockIdx.x * 16 + wave * 4 + g;
  int p0 = rowptr[n], p1 = rowptr[n + 1];
  float4 si = *(const float4*)(s1i + (size_t)n * 4);
  float m0=-1e30f,m1=-1e30f,m2=-1e30f,m3=-1e30f;
  float s0=0.f,s1=0.f,s2=0.f,s3=0.f;
  h2 acc2[4] = {};
  for (int base = p0; base < p1; base += 64){
    float a[4][4];
#pragma unroll
    for (int ss = 0; ss < 4; ss++){
      a[ss][0] = a[ss][1] = a[ss][2] = a[ss][3] = -1e30f;
      int e = base + ss * 16 + l;
      if (e < p1){
        int d = col[e];
        float4 sj = *(const float4*)(s1j + (size_t)d * 4);
        a[ss][0] = lrelu(si.x + sj.x, 0.2f);
        a[ss][1] = lrelu(si.y + sj.y, 0.2f);
        a[ss][2] = lrelu(si.z + sj.z, 0.2f);
        a[ss][3] = lrelu(si.w + sj.w, 0.2f);
        sd[wave][g][ss * 16 + l] = d;
      }
    }
    float c0 = fmaxf(fmaxf(a[0][0], a[1][0]), fmaxf(a[2][0], a[3][0]));
    float c1 = fmaxf(fmaxf(a[0][1], a[1][1]), fmaxf(a[2][1], a[3][1]));
    float c2 = fmaxf(fmaxf(a[0][2], a[1][2]), fmaxf(a[2][2], a[3][2]));
    float c3 = fmaxf(fmaxf(a[0][3], a[1][3]), fmaxf(a[2][3], a[3][3]));
    float nm0 = fmaxf(m0, gmax16(c0)), nm1 = fmaxf(m1, gmax16(c1));
    float nm2 = fmaxf(m2, gmax16(c2)), nm3 = fmaxf(m3, gmax16(c3));
    float r0_ = __expf(m0 - nm0), r1_ = __expf(m1 - nm1);
    float r2_ = __expf(m2 - nm2), r3_ = __expf(m3 - nm3);
    float t0 = 0.f, t1 = 0.f, t2 = 0.f, t3 = 0.f;
#pragma unroll
    for (int ss = 0; ss < 4; ss++){
      float w0 = __expf(a[ss][0] - nm0), w1 = __expf(a[ss][1] - nm1);
      float w2 = __expf(a[ss][2] - nm2), w3 = __expf(a[ss][3] - nm3);
      swl[wave][g][ss * 16 + l] = make_float4(w0, w1, w2, w3);
      t0 += w0; t1 += w1; t2 += w2; t3 += w3;
    }
    s0 = s0 * r0_ + gsum16(t0); s1 = s1 * r1_ + gsum16(t1);
    s2 = s2 * r2_ + gsum16(t2); s3 = s3 * r3_ + gsum16(t3);
    m0 = nm0; m1 = nm1; m2 = nm2; m3 = nm3;
    float rsel = (hh==0)?r0_:(hh==1)?r1_:(hh==2)?r2_:r3_;
    h2 rs2 = splat(rsel);
#pragma unroll
    for (int j = 0; j < 4; j++) acc2[j] = acc2[j] * rs2;
    __builtin_amdgcn_wave_barrier();
    int cnt_ = min(p1 - base, 64);
    int e = 0;
    for (; e + 3 < cnt_; e += 4){
      int dA = sd[wave][g][e],   dB = sd[wave][g][e+1];
      int dC = sd[wave][g][e+2], dD = sd[wave][g][e+3];
      h2 wA2 = splat(((const float*)&swl[wave][g][e])[hh]);
      h2 wB2 = splat(((const float*)&swl[wave][g][e+1])[hh]);
      h2 wC2 = splat(((const float*)&swl[wave][g][e+2])[hh]);
      h2 wD2 = splat(((const float*)&swl[wave][g][e+3])[hh]);
      UB4 uA, uB, uC, uD;
      uA.u = *(const uint4*)(ht1 + (size_t)dA * 128 + 8*l);
      uB.u = *(const uint4*)(ht1 + (size_t)dB * 128 + 8*l);
      uC.u = *(const uint4*)(ht1 + (size_t)dC * 128 + 8*l);
      uD.u = *(const uint4*)(ht1 + (size_t)dD * 128 + 8*l);
#pragma unroll
      for (int j = 0; j < 4; j++){
        acc2[j] = acc2[j] + wA2 * uA.h[j] + wB2 * uB.h[j] + wC2 * uC.h[j] + wD2 * uD.h[j];
      }
    }
    for (; e < cnt_; e++){
      int dA = sd[wave][g][e];
      h2 wA2 = splat(((const float*)&swl[wave][g][e])[hh]);
      UB4 uA;
      uA.u = *(const uint4*)(ht1 + (size_t)dA * 128 + 8*l);
#pragma unroll
      for (int j = 0; j < 4; j++) acc2[j] = acc2[j] + wA2 * uA.h[j];
    }
    __builtin_amdgcn_wave_barrier();
  }
  float ssel = (hh==0)?s0:(hh==1)?s1:(hh==2)?s2:s3;
  float rinv = 1.f / (ssel + 1e-16f);
  float accf[8];
#pragma unroll
  for (int j = 0; j < 4; j++){ accf[2*j] = (float)acc2[j].x; accf[2*j+1] = (float)acc2[j].y; }
  float sum2 = 0.f;
#pragma unroll
  for (int j = 0; j < 8; j++){ accf[j] *= rinv; sum2 = fmaf(accf[j], accf[j], sum2); }
  sum2 = gsum16(sum2);
  float nn = fmaxf(sqrtf(sum2), MINNRM);
  float un = tanhf(nn);
  float f_, uN;
  if (un > MAXN){ f_ = MAXN / nn; uN = MAXN; } else { f_ = un / nn; uN = un; }
  float lg = artanh_c(uN) / fmaxf(uN, MINNRM);
  float tt[8]; float sum2b = 0.f;
#pragma unroll
  for (int j = 0; j < 8; j++){ tt[j] = lrelu(accf[j] * f_ * lg, 0.01f); sum2b = fmaf(tt[j], tt[j], sum2b); }
  sum2b = gsum16(sum2b);
  float nn2 = fmaxf(sqrtf(sum2b), MINNRM);
  float un2 = tanhf(nn2);
  float f2, nm2v;
  if (un2 > MAXN){ f2 = MAXN / nn2; nm2v = MAXN; } else { f2 = un2 / nn2; nm2v = un2; }
  union { uint4 u; __half2 h[4]; } st;
  st.h[0] = __floats2half2_rn(tt[0]*f2, tt[1]*f2);
  st.h[1] = __floats2half2_rn(tt[2]*f2, tt[3]*f2);
  st.h[2] = __floats2half2_rn(tt[4]*f2, tt[5]*f2);
  st.h[3] = __floats2half2_rn(tt[6]*f2, tt[7]*f2);
  *(uint4*)(hacth + (size_t)n * 128 + 8*l) = st.u;
  if (l == 0) xn1[n] = nm2v;
}

// ---- agg2: 16-lane group/node; superchunk; packed-fp16 gather; mean heads ----
__global__ __launch_bounds__(256) void k_agg2(const int* __restrict__ rowptr, const int* __restrict__ col,
    const __half* __restrict__ ht2, const float* __restrict__ s2i, const float* __restrict__ s2j,
    float* __restrict__ out){
  __shared__ int    sd[4][4][68];
  __shared__ float4 swl[4][4][66];
  int tid = threadIdx.x, wave = tid >> 6, lane = tid & 63;
  int g = lane >> 4, l = lane & 15, hh = l >> 2;
  int n = blockIdx.x * 16 + wave * 4 + g;
  int p0 = rowptr[n], p1 = rowptr[n + 1];
  float4 si = *(const float4*)(s2i + (size_t)n * 4);
  float m0=-1e30f,m1=-1e30f,m2=-1e30f,m3=-1e30f;
  float s0=0.f,s1=0.f,s2=0.f,s3=0.f;
  h2 acc2[8] = {};
  for (int base = p0; base < p1; base += 64){
    float a[4][4];
#pragma unroll
    for (int ss = 0; ss < 4; ss++){
      a[ss][0] = a[ss][1] = a[ss][2] = a[ss][3] = -1e30f;
      int e = base + ss * 16 + l;
      if (e < p1){
        int d = col[e];
        float4 sj = *(const float4*)(s2j + (size_t)d * 4);
        a[ss][0] = lrelu(si.x + sj.x, 0.2f);
        a[ss][1] = lrelu(si.y + sj.y, 0.2f);
        a[ss][2] = lrelu(si.z + sj.z, 0.2f);
        a[ss][3] = lrelu(si.w + sj.w, 0.2f);
        sd[wave][g][ss * 16 + l] = d;
      }
    }
    float c0 = fmaxf(fmaxf(a[0][0], a[1][0]), fmaxf(a[2][0], a[3][0]));
    float c1 = fmaxf(fmaxf(a[0][1], a[1][1]), fmaxf(a[2][1], a[3][1]));
    float c2 = fmaxf(fmaxf(a[0][2], a[1][2]), fmaxf(a[2][2], a[3][2]));
    float c3 = fmaxf(fmaxf(a[0][3], a[1][3]), fmaxf(a[2][3], a[3][3]));
    float nm0 = fmaxf(m0, gmax16(c0)), nm1 = fmaxf(m1, gmax16(c1));
    float nm2 = fmaxf(m2, gmax16(c2)), nm3 = fmaxf(m3, gmax16(c3));
    float r0_ = __expf(m0 - nm0), r1_ = __expf(m1 - nm1);
    float r2_ = __expf(m2 - nm2), r3_ = __expf(m3 - nm3);
    float t0 = 0.f, t1 = 0.f, t2 = 0.f, t3 = 0.f;
#pragma unroll
    for (int ss = 0; ss < 4; ss++){
      float w0 = __expf(a[ss][0] - nm0), w1 = __expf(a[ss][1] - nm1);
      float w2 = __expf(a[ss][2] - nm2), w3 = __expf(a[ss][3] - nm3);
      swl[wave][g][ss * 16 + l] = make_float4(w0, w1, w2, w3);
      t0 += w0; t1 += w1; t2 += w2; t3 += w3;
    }
    s0 = s0 * r0_ + gsum16(t0); s1 = s1 * r1_ + gsum16(t1);
    s2 = s2 * r2_ + gsum16(t2); s3 = s3 * r3_ + gsum16(t3);
    m0 = nm0; m1 = nm1; m2 = nm2; m3 = nm3;
    float rsel = (hh==0)?r0_:(hh==1)?r1_:(hh==2)?r2_:r3_;
    h2 rs2 = splat(rsel);
#pragma unroll
    for (int j = 0; j < 8; j++) acc2[j] = acc2[j] * rs2;
    __builtin_amdgcn_wave_barrier();
    int cnt_ = min(p1 - base, 64);
    int e = 0;
    for (; e + 3 < cnt_; e += 4){
      int dA = sd[wave][g][e],   dB = sd[wave][g][e+1];
      int dC = sd[wave][g][e+2], dD = sd[wave][g][e+3];
      h2 wA2 = splat(((const float*)&swl[wave][g][e])[hh]);
      h2 wB2 = splat(((const float*)&swl[wave][g][e+1])[hh]);
      h2 wC2 = splat(((const float*)&swl[wave][g][e+2])[hh]);
      h2 wD2 = splat(((const float*)&swl[wave][g][e+3])[hh]);
      const __half* pA = ht2 + (size_t)dA * 256 + 16*l;
      const __half* pB = ht2 + (size_t)dB * 256 + 16*l;
      const __half* pC = ht2 + (size_t)dC * 256 + 16*l;
      const __half* pD = ht2 + (size_t)dD * 256 + 16*l;
      UB4 uA0, uA1, uB0, uB1, uC0, uC1, uD0, uD1;
      uA0.u = *(const uint4*)pA; uA1.u = *(const uint4*)(pA + 8);
      uB0.u = *(const uint4*)pB; uB1.u = *(const uint4*)(pB + 8);
      uC0.u = *(const uint4*)pC; uC1.u = *(const uint4*)(pC + 8);
      uD0.u = *(const uint4*)pD; uD1.u = *(const uint4*)(pD + 8);
#pragma unroll
      for (int j = 0; j < 4; j++){
        acc2[j]   = acc2[j]   + wA2 * uA0.h[j] + wB2 * uB0.h[j] + wC2 * uC0.h[j] + wD2 * uD0.h[j];
        acc2[4+j] = acc2[4+j] + wA2 * uA1.h[j] + wB2 * uB1.h[j] + wC2 * uC1.h[j] + wD2 * uD1.h[j];
      }
    }
    for (; e < cnt_; e++){
      int dA = sd[wave][g][e];
      h2 wA2 = splat(((const float*)&swl[wave][g][e])[hh]);
      const __half* pA = ht2 + (size_t)dA * 256 + 16*l;
      UB4 uA0, uA1;
      uA0.u = *(const uint4*)pA; uA1.u = *(const uint4*)(pA + 8);
#pragma unroll
      for (int j = 0; j < 4; j++){
        acc2[j]   = acc2[j]   + wA2 * uA0.h[j];
        acc2[4+j] = acc2[4+j] + wA2 * uA1.h[j];
      }
    }
    __builtin_amdgcn_wave_barrier();
  }
  float ssel = (hh==0)?s0:(hh==1)?s1:(hh==2)?s2:s3;
  float rinv = 1.f / (ssel + 1e-16f);
  float accf[16];
#pragma unroll
  for (int j = 0; j < 4; j++){
    accf[2*j]     = (float)acc2[j].x;   accf[2*j+1]   = (float)acc2[j].y;
    accf[8+2*j]   = (float)acc2[4+j].x; accf[8+2*j+1] = (float)acc2[4+j].y;
  }
  float mj[16]; float sum2 = 0.f;
#pragma unroll
  for (int j = 0; j < 16; j++){
    float v = accf[j] * rinv;
    v += __shfl_xor(v, 4, 64);
    v += __shfl_xor(v, 8, 64);
    mj[j] = 0.25f * v;
    sum2 = fmaf(mj[j], mj[j], sum2);
  }
  sum2 = 0.25f * gsum16(sum2);
  float nn = fmaxf(sqrtf(sum2), MINNRM);
  float un = tanhf(nn);
  float f_, uN;
  if (un > MAXN){ f_ = MAXN / nn; uN = MAXN; } else { f_ = un / nn; uN = un; }
  float lg = artanh_c(uN) / fmaxf(uN, MINNRM);
  float tt[16]; float sum2b = 0.f;
#pragma unroll
  for (int j = 0; j < 16; j++){ tt[j] = lrelu(mj[j] * f_ * lg, 0.01f); sum2b = fmaf(tt[j], tt[j], sum2b); }
  sum2b = 0.25f * gsum16(sum2b);
  float nn2 = fmaxf(sqrtf(sum2b), MINNRM);
  float un2 = tanhf(nn2);
  float f2 = (un2 > MAXN) ? (MAXN / nn2) : (un2 / nn2);
  float uN2 = fminf(un2, MAXN);
  float lg2 = artanh_c(uN2) / fmaxf(uN2, MINNRM);
  if (hh == 0){
    float o[16];
#pragma unroll
    for (int j = 0; j < 16; j++) o[j] = tt[j] * f2 * lg2;
    float* op = out + (size_t)n * 64 + 16*l;
    *(float4*)op      = *(float4*)&o[0];
    *(float4*)(op+4)  = *(float4*)&o[4];
    *(float4*)(op+8)  = *(float4*)&o[8];
    *(float4*)(op+12) = *(float4*)&o[12];
  }
}

extern "C" void kernel_launch(void* const* d_in, const int* in_sizes, int n_in,
                              void* d_out, int out_size, void* d_ws, size_t ws_size,
                              hipStream_t stream){
  const float* x   = (const float*)d_in[0];
  const float* Wl  = (const float*)d_in[1];
  const float* bl  = (const float*)d_in[2];
  const float* W1  = (const float*)d_in[3];
  const float* b1  = (const float*)d_in[4];
  const float* ai1 = (const float*)d_in[5];
  const float* aj1 = (const float*)d_in[6];
  const float* W2  = (const float*)d_in[7];
  const float* b2  = (const float*)d_in[8];
  const float* ai2 = (const float*)d_in[9];
  const float* aj2 = (const float*)d_in[10];
  const int*   ei  = (const int*)d_in[11];
  float* out = (float*)d_out;
  float* ws  = (float*)d_ws;

  __half* h0h   = (__half*)(ws);
  __half* ht1h  = (__half*)(ws + 1600000);
  __half* hacth = (__half*)(ws + 4800000);
  __half* ht2h  = (__half*)(ws + 8000000);
  float* xn0    = ws + 14400000;
  float* xn1    = ws + 14450000;
  float* s1i    = ws + 14500000;
  float* s1j    = ws + 14700000;
  float* hbx1   = ws + 14900000;
  float* hbx2   = ws + 14900144;
  int* rowptr   = (int*)(ws + 14900416);   // NN+1
  int* cnt      = rowptr + NN + 1;         // NN
  int* col      = cnt + NN;                // NE
  int* part     = col + NE;                // NN
  int* bsum     = part + NN;               // NBLK
  int* rank     = bsum + NBLK;             // NE
  __half* Wlh   = (__half*)(ws + 16800000);
  __half* W1h   = (__half*)(ws + 16810000);
  __half* W2m   = (__half*)(ws + 16820000); // [256][128] fp16 row-major

  hipMemsetAsync(cnt, 0, NN * sizeof(int), stream);
  kprep<<<162 + HB, 256, 0, stream>>>(b1, ai1, aj1, hbx1, b2, ai2, aj2, hbx2,
                                      Wl, Wlh, W1, W1h, W2, W2m, ei, cnt, rank);
  kB<<<NBLK + G0B, 256, 0, stream>>>(cnt, part, bsum, x, Wlh, bl, h0h, xn0);
  kscan2<<<1, 256, 0, stream>>>(bsum);
  kscan3<<<NBLK, SCAN_B, 0, stream>>>(part, bsum, cnt, rowptr);
  kE<<<G0B + HB, 256, 0, stream>>>(ei, rowptr, rank, col, h0h, W1h, xn0, hbx1, ai1, aj1, ht1h, s1i, s1j);
  k_agg1<<<NN / 16, 256, 0, stream>>>(rowptr, col, ht1h, s1i, s1j, hacth, xn1);
  kg2m<<<(NN + 31) / 32, 256, 0, stream>>>(hacth, W2m, xn1, hbx2, ai2, aj2, ht2h, s1i, s1j);
  k_agg2<<<NN / 16, 256, 0, stream>>>(rowptr, col, ht2h, s1i, s1j, out);
}

// Round 18
// 221.731 us; speedup vs baseline: 1.2443x; 1.2443x over previous
//
#include <hip/hip_runtime.h>
#include <hip/hip_fp16.h>

#define NN 50000
#define NER 800000
#define NE 850000
#define MAXN 0.996f
#define MINNRM 1e-15f
#define SCAN_B 256
#define NBLK ((NN + SCAN_B - 1) / SCAN_B)   // 196
#define HB ((NE + 255) / 256)               // 3321
#define G0B ((NN + 63) / 64)                // 782

typedef _Float16 h2 __attribute__((ext_vector_type(2)));
typedef _Float16 h8 __attribute__((ext_vector_type(8)));
typedef float f32x4 __attribute__((ext_vector_type(4)));
union UB4 { uint4 u; h2 h[4]; };

__device__ __forceinline__ h2 f2h2(float a, float b){ h2 r; r.x=(_Float16)a; r.y=(_Float16)b; return r; }
__device__ __forceinline__ h2 splat(float a){ h2 r; r.x=(_Float16)a; r.y=(_Float16)a; return r; }

__device__ __forceinline__ float gsum16(float v){
  v += __shfl_xor(v, 1, 64); v += __shfl_xor(v, 2, 64);
  v += __shfl_xor(v, 4, 64); v += __shfl_xor(v, 8, 64);
  return v;
}
__device__ __forceinline__ float gmax16(float v){
  v = fmaxf(v, __shfl_xor(v, 1, 64)); v = fmaxf(v, __shfl_xor(v, 2, 64));
  v = fmaxf(v, __shfl_xor(v, 4, 64)); v = fmaxf(v, __shfl_xor(v, 8, 64));
  return v;
}
__device__ __forceinline__ float artanh_c(float t){
  t = fminf(t, 1.0f - 1e-7f);
  return 0.5f * (log1pf(t) - log1pf(-t));
}
__device__ __forceinline__ float lrelu(float t, float s){ return t >= 0.f ? t : s * t; }

__device__ void bias_blk(const float* b, const float* ai, const float* aj, int L, int HS, float* hbx){
  __shared__ float red[256];
  __shared__ float hai[4], haj[4];
  int t = threadIdx.x;
  float v = (t < L) ? b[t] : 0.f;
  red[t] = v * v; __syncthreads();
  for (int s = 128; s; s >>= 1){ if (t < s) red[t] += red[t + s]; __syncthreads(); }
  float n  = fmaxf(sqrtf(red[0]), MINNRM);
  float un = tanhf(n);
  float nn = un;
  float f  = un / n;
  if (un > MAXN){ f = MAXN / n; nn = MAXN; }
  float hb = v * f;
  if (t < L) hbx[t] = hb;
  if (t < 4){ hai[t] = 0.f; haj[t] = 0.f; }
  __syncthreads();
  if (t < L){
    int h = t / HS;
    atomicAdd(&hai[h], hb * ai[t]);
    atomicAdd(&haj[h], hb * aj[t]);
  }
  __syncthreads();
  if (t == 0) hbx[L] = nn * nn;
  if (t < 4){ hbx[L + 1 + t] = hai[t]; hbx[L + 5 + t] = haj[t]; }
}

__device__ __forceinline__ void wconv(const float* in, __half* outp, int Nr, int Kc, int i){
  int tot = Nr * (Kc >> 1);
  if (i >= tot) return;
  int kp = i / Nr, n = i % Nr;
  __half2 v;
  v.x = __float2half(in[(size_t)n * Kc + 2 * kp]);
  v.y = __float2half(in[(size_t)n * Kc + 2 * kp + 1]);
  ((__half2*)outp)[i] = v;
}

// ---- fused prep ----
__global__ __launch_bounds__(256) void kprep(
    const float* __restrict__ b1, const float* __restrict__ ai1, const float* __restrict__ aj1, float* __restrict__ hbx1,
    const float* __restrict__ b2, const float* __restrict__ ai2, const float* __restrict__ aj2, float* __restrict__ hbx2,
    const float* __restrict__ Wl, __half* __restrict__ Wlh,
    const float* __restrict__ W1, __half* __restrict__ W1h,
    const float* __restrict__ W2, __half* __restrict__ W2m,
    const int* __restrict__ ei, int* __restrict__ cnt, int* __restrict__ rank){
  int bid = blockIdx.x, tid = threadIdx.x;
  if (bid == 0){ bias_blk(b1, ai1, aj1, 128, 32, hbx1); return; }
  if (bid == 1){ bias_blk(b2, ai2, aj2, 256, 64, hbx2); return; }
  if (bid < 18){ wconv(Wl, Wlh, 64, 128, (bid - 2) * 256 + tid); return; }
  if (bid < 34){ wconv(W1, W1h, 128, 64, (bid - 18) * 256 + tid); return; }
  if (bid < 162){
    int i = (bid - 34) * 256 + tid;
    if (i < 256 * 128) W2m[i] = __float2half(W2[i]);
    return;
  }
  int e = (bid - 162) * 256 + tid;
  if (e >= NE) return;
  int s = (e < NER) ? ei[e] : (e - NER);
  rank[e] = atomicAdd(&cnt[s], 1);
}

// ---- k_g0 body: thread-per-row epilogue ----
__device__ void kg0_body(int bid, const float* __restrict__ x, const __half* __restrict__ Wlh,
                         const float* __restrict__ bl, __half* __restrict__ h0h,
                         float* __restrict__ xn0){
  __shared__ __align__(16) h2 As2[16][68];
  __shared__ __align__(16) h2 Bs2[16][68];
  __shared__ float red[64][2];
  __shared__ float fsc[64];
  int tid = threadIdx.x, wave = tid >> 6, lane = tid & 63;
  int wr = wave >> 1, wc = wave & 1, lr = lane >> 3, lc = lane & 7;
  int row0 = bid * 64;
  int r0 = wr * 32 + lr * 4, c0 = wc * 32 + lc * 4;
  float acc[4][4] = {};
  int am = tid >> 2, aq = tid & 3;
  int bkp = tid >> 4, bn4 = (tid & 15) * 4;
  const uint* Wlu = (const uint*)Wlh;
  float4 ra0, ra1; uint4 rb;
  {
    int row = row0 + am;
    ra0 = make_float4(0.f,0.f,0.f,0.f); ra1 = ra0;
    if (row < NN){
      ra0 = *(const float4*)(x + (size_t)row * 128 + aq * 8);
      ra1 = *(const float4*)(x + (size_t)row * 128 + aq * 8 + 4);
    }
    rb = *(const uint4*)(Wlu + (size_t)bkp * 64 + bn4);
  }
  for (int ks = 0; ks < 4; ks++){
    __syncthreads();
    As2[aq*4+0][am] = f2h2(ra0.x, ra0.y);
    As2[aq*4+1][am] = f2h2(ra0.z, ra0.w);
    As2[aq*4+2][am] = f2h2(ra1.x, ra1.y);
    As2[aq*4+3][am] = f2h2(ra1.z, ra1.w);
    *(uint4*)&Bs2[bkp][bn4] = rb;
    __syncthreads();
    if (ks < 3){
      int k0 = (ks + 1) * 32;
      int row = row0 + am;
      ra0 = make_float4(0.f,0.f,0.f,0.f); ra1 = ra0;
      if (row < NN){
        ra0 = *(const float4*)(x + (size_t)row * 128 + k0 + aq * 8);
        ra1 = *(const float4*)(x + (size_t)row * 128 + k0 + aq * 8 + 4);
      }
      rb = *(const uint4*)(Wlu + (size_t)((ks + 1) * 16 + bkp) * 64 + bn4);
    }
#pragma unroll
    for (int kp = 0; kp < 16; kp++){
      UB4 av, bv;
      av.u = *(const uint4*)&As2[kp][r0];
      bv.u = *(const uint4*)&Bs2[kp][c0];
#pragma unroll
      for (int i = 0; i < 4; i++)
#pragma unroll
        for (int j = 0; j < 4; j++)
          acc[i][j] = __builtin_amdgcn_fdot2(av.h[i], bv.h[j], acc[i][j], false);
    }
  }
  float bb[4];
  *(float4*)&bb[0] = *(const float4*)(bl + c0);
#pragma unroll
  for (int i = 0; i < 4; i++){
    float rs = 0.f;
#pragma unroll
    for (int j = 0; j < 4; j++){ acc[i][j] += bb[j]; rs = fmaf(acc[i][j], acc[i][j], rs); }
    rs += __shfl_xor(rs, 1, 64);
    rs += __shfl_xor(rs, 2, 64);
    rs += __shfl_xor(rs, 4, 64);
    if (lc == 0) red[r0 + i][wc] = rs;
  }
  __syncthreads();
  if (tid < 64){
    int row = row0 + tid;
    if (row < NN){
      float rs = red[tid][0] + red[tid][1];
      float n  = fmaxf(sqrtf(rs), MINNRM);
      float un = tanhf(n);
      float f, nm;
      if (un > MAXN){ f = MAXN / n; nm = MAXN; } else { f = un / n; nm = un; }
      fsc[tid] = f;
      xn0[row] = nm;
    }
  }
  __syncthreads();
#pragma unroll
  for (int i = 0; i < 4; i++){
    int row = row0 + r0 + i;
    if (row >= NN) continue;
    float f = fsc[r0 + i];
    union { uint2 u; __half2 h[2]; } st;
    st.h[0] = __floats2half2_rn(acc[i][0] * f, acc[i][1] * f);
    st.h[1] = __floats2half2_rn(acc[i][2] * f, acc[i][3] * f);
    *(uint2*)(h0h + (size_t)row * 64 + c0) = st.u;
  }
}

// ---- merged: kscan1 + k_g0 ----
__global__ __launch_bounds__(256) void kB(const int* __restrict__ cnt,
                                          int* __restrict__ part, int* __restrict__ bsum,
                                          const float* __restrict__ x, const __half* __restrict__ Wlh,
                                          const float* __restrict__ bl, __half* __restrict__ h0h,
                                          float* __restrict__ xn0){
  int bid = blockIdx.x;
  if (bid < NBLK){
    __shared__ int sh[SCAN_B];
    int t = threadIdx.x;
    int i = bid * SCAN_B + t;
    int v = (i < NN) ? cnt[i] : 0;
    sh[t] = v; __syncthreads();
    for (int d = 1; d < SCAN_B; d <<= 1){
      int u = (t >= d) ? sh[t - d] : 0;
      __syncthreads();
      sh[t] += u;
      __syncthreads();
    }
    if (i < NN) part[i] = sh[t];
    if (t == SCAN_B - 1) bsum[bid] = sh[t];
    return;
  }
  kg0_body(bid - NBLK, x, Wlh, bl, h0h, xn0);
}

__global__ __launch_bounds__(256) void kscan2(int* __restrict__ bsum){
  __shared__ int sh[256];
  int t = threadIdx.x;
  int v = (t < NBLK) ? bsum[t] : 0;
  sh[t] = v; __syncthreads();
  for (int d = 1; d < 256; d <<= 1){
    int u = (t >= d) ? sh[t - d] : 0;
    __syncthreads();
    sh[t] += u;
    __syncthreads();
  }
  if (t < NBLK) bsum[t] = sh[t];
}

__global__ __launch_bounds__(SCAN_B) void kscan3(const int* __restrict__ part, const int* __restrict__ bsum,
                                                 const int* __restrict__ cnt, int* __restrict__ rowptr){
  int t = threadIdx.x;
  int i = blockIdx.x * SCAN_B + t;
  if (i < NN){
    int base = blockIdx.x ? bsum[blockIdx.x - 1] : 0;
    rowptr[i] = base + part[i] - cnt[i];
  }
  if (i == 0) rowptr[NN] = bsum[NBLK - 1];
}

// ---- kg1f body: thread-per-row epilogue ----
__device__ void kg1f_body(int bid, const __half* __restrict__ Ah, const __half* __restrict__ W1h,
    const float* __restrict__ xn0, const float* __restrict__ hbx,
    const float* __restrict__ ai, const float* __restrict__ aj,
    __half* __restrict__ ht1, float* __restrict__ s1i, float* __restrict__ s1j){
  __shared__ __align__(16) h2 As2[16][68];
  __shared__ __align__(16) h2 Bs2[16][132];
  __shared__ float red[64][12];
  __shared__ float pq1[64][4];
  int tid = threadIdx.x, wave = tid >> 6, lane = tid & 63;
  int wr = wave >> 1, wc = wave & 1, lr = lane >> 3, lc = lane & 7;
  int row0 = bid * 64;
  int r0 = wr * 32 + lr * 4, c0 = wc * 64 + lc * 8;
  float acc[4][8] = {};
  const uint* Au = (const uint*)Ah;
  const uint* Bu = (const uint*)W1h;
  int akp = tid & 15, am0 = (tid >> 4) * 4;
  int bkp = tid >> 4, bcol = (tid & 15) * 4;
  uint ua0, ua1, ua2, ua3; uint4 ub0, ub1;
  {
    int r;
    ua0 = ua1 = ua2 = ua3 = 0u;
    r = row0 + am0 + 0; if (r < NN) ua0 = Au[(size_t)r * 32 + akp];
    r = row0 + am0 + 1; if (r < NN) ua1 = Au[(size_t)r * 32 + akp];
    r = row0 + am0 + 2; if (r < NN) ua2 = Au[(size_t)r * 32 + akp];
    r = row0 + am0 + 3; if (r < NN) ua3 = Au[(size_t)r * 32 + akp];
    ub0 = *(const uint4*)(Bu + (size_t)bkp * 128 + bcol);
    ub1 = *(const uint4*)(Bu + (size_t)bkp * 128 + bcol + 64);
  }
  for (int ks = 0; ks < 2; ks++){
    __syncthreads();
    { uint4 av4; av4.x = ua0; av4.y = ua1; av4.z = ua2; av4.w = ua3;
      *(uint4*)&As2[akp][am0] = av4; }
    *(uint4*)&Bs2[bkp][bcol]      = ub0;
    *(uint4*)&Bs2[bkp][bcol + 64] = ub1;
    __syncthreads();
    if (ks < 1){
      int r;
      ua0 = ua1 = ua2 = ua3 = 0u;
      r = row0 + am0 + 0; if (r < NN) ua0 = Au[(size_t)r * 32 + 16 + akp];
      r = row0 + am0 + 1; if (r < NN) ua1 = Au[(size_t)r * 32 + 16 + akp];
      r = row0 + am0 + 2; if (r < NN) ua2 = Au[(size_t)r * 32 + 16 + akp];
      r = row0 + am0 + 3; if (r < NN) ua3 = Au[(size_t)r * 32 + 16 + akp];
      ub0 = *(const uint4*)(Bu + (size_t)(16 + bkp) * 128 + bcol);
      ub1 = *(const uint4*)(Bu + (size_t)(16 + bkp) * 128 + bcol + 64);
    }
#pragma unroll
    for (int kp = 0; kp < 16; kp++){
      UB4 av, bv0, bv1;
      av.u  = *(const uint4*)&As2[kp][r0];
      bv0.u = *(const uint4*)&Bs2[kp][c0];
      bv1.u = *(const uint4*)&Bs2[kp][c0 + 4];
#pragma unroll
      for (int i = 0; i < 4; i++){
#pragma unroll
        for (int j = 0; j < 4; j++)
          acc[i][j] = __builtin_amdgcn_fdot2(av.h[i], bv0.h[j], acc[i][j], false);
#pragma unroll
        for (int j = 4; j < 8; j++)
          acc[i][j] = __builtin_amdgcn_fdot2(av.h[i], bv1.h[j - 4], acc[i][j], false);
      }
    }
  }
  float hbv[8], aiv[8], ajv[8];
  *(float4*)&hbv[0] = *(const float4*)(hbx + c0); *(float4*)&hbv[4] = *(const float4*)(hbx + c0 + 4);
  *(float4*)&aiv[0] = *(const float4*)(ai + c0);  *(float4*)&aiv[4] = *(const float4*)(ai + c0 + 4);
  *(float4*)&ajv[0] = *(const float4*)(aj + c0);  *(float4*)&ajv[4] = *(const float4*)(aj + c0 + 4);
  int head = wc * 2 + (lc >> 2);
#pragma unroll
  for (int i = 0; i < 4; i++){
    float p1=0.f, p2=0.f, pai=0.f, paj=0.f;
#pragma unroll
    for (int j = 0; j < 8; j++){
      float a = acc[i][j];
      p1 += a*a; p2 += a*hbv[j]; pai += a*aiv[j]; paj += a*ajv[j];
    }
    p1 += __shfl_xor(p1,1,64); p1 += __shfl_xor(p1,2,64); p1 += __shfl_xor(p1,4,64);
    p2 += __shfl_xor(p2,1,64); p2 += __shfl_xor(p2,2,64); p2 += __shfl_xor(p2,4,64);
    pai += __shfl_xor(pai,1,64); pai += __shfl_xor(pai,2,64);
    paj += __shfl_xor(paj,1,64); paj += __shfl_xor(paj,2,64);
    int rloc = r0 + i;
    if (lc == 0){ red[rloc][wc] = p1; red[rloc][2+wc] = p2; }
    if ((lc & 3) == 0){ red[rloc][4+head] = pai; red[rloc][8+head] = paj; }
  }
  __syncthreads();
  if (tid < 64){
    int row = row0 + tid;
    if (row < NN){
      float b2 = hbx[128];
      float S1 = red[tid][0] + red[tid][1];
      float S2 = red[tid][2] + red[tid][3];
      float xn = fmaxf(xn0[row], MINNRM);
      float r_art = artanh_c(xn);
      float mxn = fmaxf(sqrtf(S1), MINNRM);
      float tn = tanhf(mxn / xn * r_art);
      float sc_ = tn / mxn;
      float rn = tn;
      if (rn > MAXN){ sc_ *= MAXN / rn; rn = MAXN; }
      float a2r = rn * rn;
      float ab = sc_ * S2;
      float co1 = 1.f + 2.f*ab + b2, co2 = 1.f - a2r;
      float den = fmaxf(1.f + 2.f*ab + a2r*b2, MINNRM);
      float P = co1 * sc_ / den, Q = co2 / den;
      float hn2 = P*P*S1 + 2.f*P*Q*S2 + Q*Q*b2;
      float hn = fmaxf(sqrtf(hn2), MINNRM);
      if (hn > MAXN){ float R = MAXN / hn; P *= R; Q *= R; hn = MAXN; }
      float lf = artanh_c(hn) / hn;
      pq1[tid][0] = P; pq1[tid][1] = Q; pq1[tid][2] = lf;
#pragma unroll
      for (int h = 0; h < 4; h++){
        s1i[row*4+h] = lf * (P * red[tid][4+h] + Q * hbx[129+h]);
        s1j[row*4+h] = lf * (P * red[tid][8+h] + Q * hbx[133+h]);
      }
    }
  }
  __syncthreads();
#pragma unroll
  for (int i = 0; i < 4; i++){
    int row = row0 + r0 + i;
    if (row >= NN) continue;
    int rloc = r0 + i;
    float P = pq1[rloc][0], Q = pq1[rloc][1], lf = pq1[rloc][2];
    union { __half h[8]; float4 f4; } ho;
#pragma unroll
    for (int j = 0; j < 8; j++) ho.h[j] = __float2half(lf * (P * acc[i][j] + Q * hbv[j]));
    *(float4*)(ht1 + (size_t)row * 128 + c0) = ho.f4;
  }
}

// ---- merged: kg1f + rank-based fill ----
__global__ __launch_bounds__(256) void kE(const int* __restrict__ ei, const int* __restrict__ rowptr,
    const int* __restrict__ rank, int* __restrict__ col,
    const __half* __restrict__ Ah, const __half* __restrict__ W1h,
    const float* __restrict__ xn0, const float* __restrict__ hbx,
    const float* __restrict__ ai, const float* __restrict__ aj,
    __half* __restrict__ ht1, float* __restrict__ s1i, float* __restrict__ s1j){
  int bid = blockIdx.x;
  if (bid >= G0B){
    int e = (bid - G0B) * 256 + threadIdx.x;
    if (e >= NE) return;
    int s, d;
    if (e < NER){ s = ei[e]; d = ei[NER + e]; }
    else { s = e - NER; d = s; }
    col[rowptr[s] + rank[e]] = d;
    return;
  }
  kg1f_body(bid, Ah, W1h, xn0, hbx, ai, aj, ht1, s1i, s1j);
}

// ---- kg2m: MFMA GEMM + thread-per-row epilogue ----
__global__ __launch_bounds__(256) void kg2m(const __half* __restrict__ Ah, const __half* __restrict__ W2m,
    const float* __restrict__ xn1, const float* __restrict__ hbx,
    const float* __restrict__ ai, const float* __restrict__ aj,
    __half* __restrict__ ht2, float* __restrict__ s2i, float* __restrict__ s2j){
  __shared__ float red[32][16];
  __shared__ float pqlf[32][4];
  int tid = threadIdx.x, w = tid >> 6, lane = tid & 63;
  int lm = lane & 15, lg = lane >> 4;
  int row0 = blockIdx.x * 32;
  const _Float16* Af = (const _Float16*)Ah;
  const _Float16* Bf = (const _Float16*)W2m;
  const _Float16* A0 = Af + (size_t)(row0 + lm) * 128 + lg * 8;
  h8 a00 = *(const h8*)(A0);
  h8 a01 = *(const h8*)(A0 + 32);
  h8 a02 = *(const h8*)(A0 + 64);
  h8 a03 = *(const h8*)(A0 + 96);
  h8 a10, a11, a12, a13;
  h8 zf = {};
  bool v1 = (row0 + 31) < NN;
  if (v1){
    const _Float16* A1 = Af + (size_t)(row0 + 16 + lm) * 128 + lg * 8;
    a10 = *(const h8*)(A1);
    a11 = *(const h8*)(A1 + 32);
    a12 = *(const h8*)(A1 + 64);
    a13 = *(const h8*)(A1 + 96);
  } else { a10 = zf; a11 = zf; a12 = zf; a13 = zf; }
  f32x4 c00 = {0.f,0.f,0.f,0.f}, c01 = c00, c02 = c00, c03 = c00;
  f32x4 c10 = c00, c11 = c00, c12 = c00, c13 = c00;
#define DO_CT(CT, C0, C1) { \
    const _Float16* Bp = Bf + (size_t)(w * 64 + (CT) * 16 + lm) * 128 + lg * 8; \
    h8 b0 = *(const h8*)(Bp); \
    h8 b1 = *(const h8*)(Bp + 32); \
    h8 b2v = *(const h8*)(Bp + 64); \
    h8 b3 = *(const h8*)(Bp + 96); \
    C0 = __builtin_amdgcn_mfma_f32_16x16x32_f16(a00, b0,  C0, 0, 0, 0); \
    C0 = __builtin_amdgcn_mfma_f32_16x16x32_f16(a01, b1,  C0, 0, 0, 0); \
    C0 = __builtin_amdgcn_mfma_f32_16x16x32_f16(a02, b2v, C0, 0, 0, 0); \
    C0 = __builtin_amdgcn_mfma_f32_16x16x32_f16(a03, b3,  C0, 0, 0, 0); \
    C1 = __builtin_amdgcn_mfma_f32_16x16x32_f16(a10, b0,  C1, 0, 0, 0); \
    C1 = __builtin_amdgcn_mfma_f32_16x16x32_f16(a11, b1,  C1, 0, 0, 0); \
    C1 = __builtin_amdgcn_mfma_f32_16x16x32_f16(a12, b2v, C1, 0, 0, 0); \
    C1 = __builtin_amdgcn_mfma_f32_16x16x32_f16(a13, b3,  C1, 0, 0, 0); }
  DO_CT(0, c00, c10)
  DO_CT(1, c01, c11)
  DO_CT(2, c02, c12)
  DO_CT(3, c03, c13)
#undef DO_CT
  int cb = w * 64 + lm;
  float hb0 = hbx[cb], hb1 = hbx[cb+16], hb2c = hbx[cb+32], hb3c = hbx[cb+48];
  float ai0 = ai[cb], ai1v = ai[cb+16], ai2c = ai[cb+32], ai3 = ai[cb+48];
  float aj0 = aj[cb], aj1v = aj[cb+16], aj2c = aj[cb+32], aj3 = aj[cb+48];
#pragma unroll
  for (int rt = 0; rt < 2; rt++){
#pragma unroll
    for (int ri = 0; ri < 4; ri++){
      float v0 = rt ? c10[ri] : c00[ri];
      float v1v = rt ? c11[ri] : c01[ri];
      float v2v = rt ? c12[ri] : c02[ri];
      float v3v = rt ? c13[ri] : c03[ri];
      float p1 = v0*v0 + v1v*v1v + v2v*v2v + v3v*v3v;
      float p2 = v0*hb0 + v1v*hb1 + v2v*hb2c + v3v*hb3c;
      float pa = v0*ai0 + v1v*ai1v + v2v*ai2c + v3v*ai3;
      float pj = v0*aj0 + v1v*aj1v + v2v*aj2c + v3v*aj3;
      p1 = gsum16(p1); p2 = gsum16(p2); pa = gsum16(pa); pj = gsum16(pj);
      if (lm == 0){
        int rloc = rt*16 + lg*4 + ri;
        red[rloc][w] = p1; red[rloc][4+w] = p2; red[rloc][8+w] = pa; red[rloc][12+w] = pj;
      }
    }
  }
  __syncthreads();
  if (tid < 32){
    int row = row0 + tid;
    if (row < NN){
      float b2s = hbx[256];
      float S1 = red[tid][0]+red[tid][1]+red[tid][2]+red[tid][3];
      float S2 = red[tid][4]+red[tid][5]+red[tid][6]+red[tid][7];
      float xn = fmaxf(xn1[row], MINNRM);
      float r_art = artanh_c(xn);
      float mxn = fmaxf(sqrtf(S1), MINNRM);
      float tn = tanhf(mxn / xn * r_art);
      float sc_ = tn / mxn;
      float rn = tn;
      if (rn > MAXN){ sc_ *= MAXN / rn; rn = MAXN; }
      float a2r = rn * rn;
      float ab = sc_ * S2;
      float co1 = 1.f + 2.f*ab + b2s, co2 = 1.f - a2r;
      float den = fmaxf(1.f + 2.f*ab + a2r*b2s, MINNRM);
      float P = co1 * sc_ / den, Q = co2 / den;
      float hn2 = P*P*S1 + 2.f*P*Q*S2 + Q*Q*b2s;
      float hn = fmaxf(sqrtf(hn2), MINNRM);
      if (hn > MAXN){ float R = MAXN / hn; P *= R; Q *= R; hn = MAXN; }
      float lf = artanh_c(hn) / hn;
      pqlf[tid][0] = P; pqlf[tid][1] = Q; pqlf[tid][2] = lf;
#pragma unroll
      for (int h = 0; h < 4; h++){
        s2i[row*4+h] = lf * (P * red[tid][8+h]  + Q * hbx[257+h]);
        s2j[row*4+h] = lf * (P * red[tid][12+h] + Q * hbx[261+h]);
      }
    }
  }
  __syncthreads();
#pragma unroll
  for (int rt = 0; rt < 2; rt++){
#pragma unroll
    for (int ri = 0; ri < 4; ri++){
      int row = row0 + rt*16 + lg*4 + ri;
      if (row >= NN) continue;
      int rloc = rt*16 + lg*4 + ri;
      float P = pqlf[rloc][0], Q = pqlf[rloc][1], lf = pqlf[rloc][2];
      float v0 = rt ? c10[ri] : c00[ri];
      float v1v = rt ? c11[ri] : c01[ri];
      float v2v = rt ? c12[ri] : c02[ri];
      float v3v = rt ? c13[ri] : c03[ri];
      __half* hp = ht2 + (size_t)row * 256 + w * 64 + lm;
      hp[0]  = __float2half(lf * (P * v0  + Q * hb0));
      hp[16] = __float2half(lf * (P * v1v + Q * hb1));
      hp[32] = __float2half(lf * (P * v2v + Q * hb2c));
      hp[48] = __float2half(lf * (P * v3v + Q * hb3c));
    }
  }
}

// ---- agg1: 16-lane group/node; superchunk; packed-fp16 gather ----
__global__ __launch_bounds__(256) void k_agg1(const int* __restrict__ rowptr, const int* __restrict__ col,
    const __half* __restrict__ ht1, const float* __restrict__ s1i, const float* __restrict__ s1j,
    __half* __restrict__ hacth, float* __restrict__ xn1){
  __shared__ int    sd[4][4][68];
  __shared__ float4 swl[4][4][66];
  int tid = threadIdx.x, wave = tid >> 6, lane = tid & 63;
  int g = lane >> 4, l = lane & 15, hh = l >> 2;
  int n = blockIdx.x * 16 + wave * 4 + g;
  int p0 = rowptr[n], p1 = rowptr[n + 1];
  float4 si = *(const float4*)(s1i + (size_t)n * 4);
  float m0=-1e30f,m1=-1e30f,m2=-1e30f,m3=-1e30f;
  float s0=0.f,s1=0.f,s2=0.f,s3=0.f;
  h2 acc2[4] = {};
  for (int base = p0; base < p1; base += 64){
    float a[4][4];
#pragma unroll
    for (int ss = 0; ss < 4; ss++){
      a[ss][0] = a[ss][1] = a[ss][2] = a[ss][3] = -1e30f;
      int e = base + ss * 16 + l;
      if (e < p1){
        int d = col[e];
        float4 sj = *(const float4*)(s1j + (size_t)d * 4);
        a[ss][0] = lrelu(si.x + sj.x, 0.2f);
        a[ss][1] = lrelu(si.y + sj.y, 0.2f);
        a[ss][2] = lrelu(si.z + sj.z, 0.2f);
        a[ss][3] = lrelu(si.w + sj.w, 0.2f);
        sd[wave][g][ss * 16 + l] = d;
      }
    }
    float c0 = fmaxf(fmaxf(a[0][0], a[1][0]), fmaxf(a[2][0], a[3][0]));
    float c1 = fmaxf(fmaxf(a[0][1], a[1][1]), fmaxf(a[2][1], a[3][1]));
    float c2 = fmaxf(fmaxf(a[0][2], a[1][2]), fmaxf(a[2][2], a[3][2]));
    float c3 = fmaxf(fmaxf(a[0][3], a[1][3]), fmaxf(a[2][3], a[3][3]));
    float nm0 = fmaxf(m0, gmax16(c0)), nm1 = fmaxf(m1, gmax16(c1));
    float nm2 = fmaxf(m2, gmax16(c2)), nm3 = fmaxf(m3, gmax16(c3));
    float r0_ = __expf(m0 - nm0), r1_ = __expf(m1 - nm1);
    float r2_ = __expf(m2 - nm2), r3_ = __expf(m3 - nm3);
    float t0 = 0.f, t1 = 0.f, t2 = 0.f, t3 = 0.f;
#pragma unroll
    for (int ss = 0; ss < 4; ss++){
      float w0 = __expf(a[ss][0] - nm0), w1 = __expf(a[ss][1] - nm1);
      float w2 = __expf(a[ss][2] - nm2), w3 = __expf(a[ss][3] - nm3);
      swl[wave][g][ss * 16 + l] = make_float4(w0, w1, w2, w3);
      t0 += w0; t1 += w1; t2 += w2; t3 += w3;
    }
    s0 = s0 * r0_ + gsum16(t0); s1 = s1 * r1_ + gsum16(t1);
    s2 = s2 * r2_ + gsum16(t2); s3 = s3 * r3_ + gsum16(t3);
    m0 = nm0; m1 = nm1; m2 = nm2; m3 = nm3;
    float rsel = (hh==0)?r0_:(hh==1)?r1_:(hh==2)?r2_:r3_;
    h2 rs2 = splat(rsel);
#pragma unroll
    for (int j = 0; j < 4; j++) acc2[j] = acc2[j] * rs2;
    __builtin_amdgcn_wave_barrier();
    int cnt_ = min(p1 - base, 64);
    int e = 0;
    for (; e + 3 < cnt_; e += 4){
      int dA = sd[wave][g][e],   dB = sd[wave][g][e+1];
      int dC = sd[wave][g][e+2], dD = sd[wave][g][e+3];
      h2 wA2 = splat(((const float*)&swl[wave][g][e])[hh]);
      h2 wB2 = splat(((const float*)&swl[wave][g][e+1])[hh]);
      h2 wC2 = splat(((const float*)&swl[wave][g][e+2])[hh]);
      h2 wD2 = splat(((const float*)&swl[wave][g][e+3])[hh]);
      UB4 uA, uB, uC, uD;
      uA.u = *(const uint4*)(ht1 + (size_t)dA * 128 + 8*l);
      uB.u = *(const uint4*)(ht1 + (size_t)dB * 128 + 8*l);
      uC.u = *(const uint4*)(ht1 + (size_t)dC * 128 + 8*l);
      uD.u = *(const uint4*)(ht1 + (size_t)dD * 128 + 8*l);
#pragma unroll
      for (int j = 0; j < 4; j++){
        acc2[j] = acc2[j] + wA2 * uA.h[j] + wB2 * uB.h[j] + wC2 * uC.h[j] + wD2 * uD.h[j];
      }
    }
    for (; e < cnt_; e++){
      int dA = sd[wave][g][e];
      h2 wA2 = splat(((const float*)&swl[wave][g][e])[hh]);
      UB4 uA;
      uA.u = *(const uint4*)(ht1 + (size_t)dA * 128 + 8*l);
#pragma unroll
      for (int j = 0; j < 4; j++) acc2[j] = acc2[j] + wA2 * uA.h[j];
    }
    __builtin_amdgcn_wave_barrier();
  }
  float ssel = (hh==0)?s0:(hh==1)?s1:(hh==2)?s2:s3;
  float rinv = 1.f / (ssel + 1e-16f);
  float accf[8];
#pragma unroll
  for (int j = 0; j < 4; j++){ accf[2*j] = (float)acc2[j].x; accf[2*j+1] = (float)acc2[j].y; }
  float sum2 = 0.f;
#pragma unroll
  for (int j = 0; j < 8; j++){ accf[j] *= rinv; sum2 = fmaf(accf[j], accf[j], sum2); }
  sum2 = gsum16(sum2);
  float nn = fmaxf(sqrtf(sum2), MINNRM);
  float un = tanhf(nn);
  float f_, uN;
  if (un > MAXN){ f_ = MAXN / nn; uN = MAXN; } else { f_ = un / nn; uN = un; }
  float lg = artanh_c(uN) / fmaxf(uN, MINNRM);
  float tt[8]; float sum2b = 0.f;
#pragma unroll
  for (int j = 0; j < 8; j++){ tt[j] = lrelu(accf[j] * f_ * lg, 0.01f); sum2b = fmaf(tt[j], tt[j], sum2b); }
  sum2b = gsum16(sum2b);
  float nn2 = fmaxf(sqrtf(sum2b), MINNRM);
  float un2 = tanhf(nn2);
  float f2, nm2v;
  if (un2 > MAXN){ f2 = MAXN / nn2; nm2v = MAXN; } else { f2 = un2 / nn2; nm2v = un2; }
  union { uint4 u; __half2 h[4]; } st;
  st.h[0] = __floats2half2_rn(tt[0]*f2, tt[1]*f2);
  st.h[1] = __floats2half2_rn(tt[2]*f2, tt[3]*f2);
  st.h[2] = __floats2half2_rn(tt[4]*f2, tt[5]*f2);
  st.h[3] = __floats2half2_rn(tt[6]*f2, tt[7]*f2);
  *(uint4*)(hacth + (size_t)n * 128 + 8*l) = st.u;
  if (l == 0) xn1[n] = nm2v;
}

// ---- agg2: 16-lane group/node; superchunk; packed-fp16 gather; mean heads ----
__global__ __launch_bounds__(256) void k_agg2(const int* __restrict__ rowptr, const int* __restrict__ col,
    const __half* __restrict__ ht2, const float* __restrict__ s2i, const float* __restrict__ s2j,
    float* __restrict__ out){
  __shared__ int    sd[4][4][68];
  __shared__ float4 swl[4][4][66];
  int tid = threadIdx.x, wave = tid >> 6, lane = tid & 63;
  int g = lane >> 4, l = lane & 15, hh = l >> 2;
  int n = blockIdx.x * 16 + wave * 4 + g;
  int p0 = rowptr[n], p1 = rowptr[n + 1];
  float4 si = *(const float4*)(s2i + (size_t)n * 4);
  float m0=-1e30f,m1=-1e30f,m2=-1e30f,m3=-1e30f;
  float s0=0.f,s1=0.f,s2=0.f,s3=0.f;
  h2 acc2[8] = {};
  for (int base = p0; base < p1; base += 64){
    float a[4][4];
#pragma unroll
    for (int ss = 0; ss < 4; ss++){
      a[ss][0] = a[ss][1] = a[ss][2] = a[ss][3] = -1e30f;
      int e = base + ss * 16 + l;
      if (e < p1){
        int d = col[e];
        float4 sj = *(const float4*)(s2j + (size_t)d * 4);
        a[ss][0] = lrelu(si.x + sj.x, 0.2f);
        a[ss][1] = lrelu(si.y + sj.y, 0.2f);
        a[ss][2] = lrelu(si.z + sj.z, 0.2f);
        a[ss][3] = lrelu(si.w + sj.w, 0.2f);
        sd[wave][g][ss * 16 + l] = d;
      }
    }
    float c0 = fmaxf(fmaxf(a[0][0], a[1][0]), fmaxf(a[2][0], a[3][0]));
    float c1 = fmaxf(fmaxf(a[0][1], a[1][1]), fmaxf(a[2][1], a[3][1]));
    float c2 = fmaxf(fmaxf(a[0][2], a[1][2]), fmaxf(a[2][2], a[3][2]));
    float c3 = fmaxf(fmaxf(a[0][3], a[1][3]), fmaxf(a[2][3], a[3][3]));
    float nm0 = fmaxf(m0, gmax16(c0)), nm1 = fmaxf(m1, gmax16(c1));
    float nm2 = fmaxf(m2, gmax16(c2)), nm3 = fmaxf(m3, gmax16(c3));
    float r0_ = __expf(m0 - nm0), r1_ = __expf(m1 - nm1);
    float r2_ = __expf(m2 - nm2), r3_ = __expf(m3 - nm3);
    float t0 = 0.f, t1 = 0.f, t2 = 0.f, t3 = 0.f;
#pragma unroll
    for (int ss = 0; ss < 4; ss++){
      float w0 = __expf(a[ss][0] - nm0), w1 = __expf(a[ss][1] - nm1);
      float w2 = __expf(a[ss][2] - nm2), w3 = __expf(a[ss][3] - nm3);
      swl[wave][g][ss * 16 + l] = make_float4(w0, w1, w2, w3);
      t0 += w0; t1 += w1; t2 += w2; t3 += w3;
    }
    s0 = s0 * r0_ + gsum16(t0); s1 = s1 * r1_ + gsum16(t1);
    s2 = s2 * r2_ + gsum16(t2); s3 = s3 * r3_ + gsum16(t3);
    m0 = nm0; m1 = nm1; m2 = nm2; m3 = nm3;
    float rsel = (hh==0)?r0_:(hh==1)?r1_:(hh==2)?r2_:r3_;
    h2 rs2 = splat(rsel);
#pragma unroll
    for (int j = 0; j < 8; j++) acc2[j] = acc2[j] * rs2;
    __builtin_amdgcn_wave_barrier();
    int cnt_ = min(p1 - base, 64);
    int e = 0;
    for (; e + 3 < cnt_; e += 4){
      int dA = sd[wave][g][e],   dB = sd[wave][g][e+1];
      int dC = sd[wave][g][e+2], dD = sd[wave][g][e+3];
      h2 wA2 = splat(((const float*)&swl[wave][g][e])[hh]);
      h2 wB2 = splat(((const float*)&swl[wave][g][e+1])[hh]);
      h2 wC2 = splat(((const float*)&swl[wave][g][e+2])[hh]);
      h2 wD2 = splat(((const float*)&swl[wave][g][e+3])[hh]);
      const __half* pA = ht2 + (size_t)dA * 256 + 16*l;
      const __half* pB = ht2 + (size_t)dB * 256 + 16*l;
      const __half* pC = ht2 + (size_t)dC * 256 + 16*l;
      const __half* pD = ht2 + (size_t)dD * 256 + 16*l;
      UB4 uA0, uA1, uB0, uB1, uC0, uC1, uD0, uD1;
      uA0.u = *(const uint4*)pA; uA1.u = *(const uint4*)(pA + 8);
      uB0.u = *(const uint4*)pB; uB1.u = *(const uint4*)(pB + 8);
      uC0.u = *(const uint4*)pC; uC1.u = *(const uint4*)(pC + 8);
      uD0.u = *(const uint4*)pD; uD1.u = *(const uint4*)(pD + 8);
#pragma unroll
      for (int j = 0; j < 4; j++){
        acc2[j]   = acc2[j]   + wA2 * uA0.h[j] + wB2 * uB0.h[j] + wC2 * uC0.h[j] + wD2 * uD0.h[j];
        acc2[4+j] = acc2[4+j] + wA2 * uA1.h[j] + wB2 * uB1.h[j] + wC2 * uC1.h[j] + wD2 * uD1.h[j];
      }
    }
    for (; e < cnt_; e++){
      int dA = sd[wave][g][e];
      h2 wA2 = splat(((const float*)&swl[wave][g][e])[hh]);
      const __half* pA = ht2 + (size_t)dA * 256 + 16*l;
      UB4 uA0, uA1;
      uA0.u = *(const uint4*)pA; uA1.u = *(const uint4*)(pA + 8);
#pragma unroll
      for (int j = 0; j < 4; j++){
        acc2[j]   = acc2[j]   + wA2 * uA0.h[j];
        acc2[4+j] = acc2[4+j] + wA2 * uA1.h[j];
      }
    }
    __builtin_amdgcn_wave_barrier();
  }
  float ssel = (hh==0)?s0:(hh==1)?s1:(hh==2)?s2:s3;
  float rinv = 1.f / (ssel + 1e-16f);
  float accf[16];
#pragma unroll
  for (int j = 0; j < 4; j++){
    accf[2*j]     = (float)acc2[j].x;   accf[2*j+1]   = (float)acc2[j].y;
    accf[8+2*j]   = (float)acc2[4+j].x; accf[8+2*j+1] = (float)acc2[4+j].y;
  }
  float mj[16]; float sum2 = 0.f;
#pragma unroll
  for (int j = 0; j < 16; j++){
    float v = accf[j] * rinv;
    v += __shfl_xor(v, 4, 64);
    v += __shfl_xor(v, 8, 64);
    mj[j] = 0.25f * v;
    sum2 = fmaf(mj[j], mj[j], sum2);
  }
  sum2 = 0.25f * gsum16(sum2);
  float nn = fmaxf(sqrtf(sum2), MINNRM);
  float un = tanhf(nn);
  float f_, uN;
  if (un > MAXN){ f_ = MAXN / nn; uN = MAXN; } else { f_ = un / nn; uN = un; }
  float lg = artanh_c(uN) / fmaxf(uN, MINNRM);
  float tt[16]; float sum2b = 0.f;
#pragma unroll
  for (int j = 0; j < 16; j++){ tt[j] = lrelu(mj[j] * f_ * lg, 0.01f); sum2b = fmaf(tt[j], tt[j], sum2b); }
  sum2b = 0.25f * gsum16(sum2b);
  float nn2 = fmaxf(sqrtf(sum2b), MINNRM);
  float un2 = tanhf(nn2);
  float f2 = (un2 > MAXN) ? (MAXN / nn2) : (un2 / nn2);
  float uN2 = fminf(un2, MAXN);
  float lg2 = artanh_c(uN2) / fmaxf(uN2, MINNRM);
  if (hh == 0){
    float o[16];
#pragma unroll
    for (int j = 0; j < 16; j++) o[j] = tt[j] * f2 * lg2;
    float* op = out + (size_t)n * 64 + 16*l;
    *(float4*)op      = *(float4*)&o[0];
    *(float4*)(op+4)  = *(float4*)&o[4];
    *(float4*)(op+8)  = *(float4*)&o[8];
    *(float4*)(op+12) = *(float4*)&o[12];
  }
}

extern "C" void kernel_launch(void* const* d_in, const int* in_sizes, int n_in,
                              void* d_out, int out_size, void* d_ws, size_t ws_size,
                              hipStream_t stream){
  const float* x   = (const float*)d_in[0];
  const float* Wl  = (const float*)d_in[1];
  const float* bl  = (const float*)d_in[2];
  const float* W1  = (const float*)d_in[3];
  const float* b1  = (const float*)d_in[4];
  const float* ai1 = (const float*)d_in[5];
  const float* aj1 = (const float*)d_in[6];
  const float* W2  = (const float*)d_in[7];
  const float* b2  = (const float*)d_in[8];
  const float* ai2 = (const float*)d_in[9];
  const float* aj2 = (const float*)d_in[10];
  const int*   ei  = (const int*)d_in[11];
  float* out = (float*)d_out;
  float* ws  = (float*)d_ws;

  __half* h0h   = (__half*)(ws);
  __half* ht1h  = (__half*)(ws + 1600000);
  __half* hacth = (__half*)(ws + 4800000);
  __half* ht2h  = (__half*)(ws + 8000000);
  float* xn0    = ws + 14400000;
  float* xn1    = ws + 14450000;
  float* s1i    = ws + 14500000;
  float* s1j    = ws + 14700000;
  float* hbx1   = ws + 14900000;
  float* hbx2   = ws + 14900144;
  int* rowptr   = (int*)(ws + 14900416);   // NN+1
  int* cnt      = rowptr + NN + 1;         // NN
  int* col      = cnt + NN;                // NE
  int* part     = col + NE;                // NN
  int* bsum     = part + NN;               // NBLK
  int* rank     = bsum + NBLK;             // NE
  __half* Wlh   = (__half*)(ws + 16800000);
  __half* W1h   = (__half*)(ws + 16810000);
  __half* W2m   = (__half*)(ws + 16820000); // [256][128] fp16 row-major

  hipMemsetAsync(cnt, 0, NN * sizeof(int), stream);
  kprep<<<162 + HB, 256, 0, stream>>>(b1, ai1, aj1, hbx1, b2, ai2, aj2, hbx2,
                                      Wl, Wlh, W1, W1h, W2, W2m, ei, cnt, rank);
  kB<<<NBLK + G0B, 256, 0, stream>>>(cnt, part, bsum, x, Wlh, bl, h0h, xn0);
  kscan2<<<1, 256, 0, stream>>>(bsum);
  kscan3<<<NBLK, SCAN_B, 0, stream>>>(part, bsum, cnt, rowptr);
  kE<<<G0B + HB, 256, 0, stream>>>(ei, rowptr, rank, col, h0h, W1h, xn0, hbx1, ai1, aj1, ht1h, s1i, s1j);
  k_agg1<<<NN / 16, 256, 0, stream>>>(rowptr, col, ht1h, s1i, s1j, hacth, xn1);
  kg2m<<<(NN + 31) / 32, 256, 0, stream>>>(hacth, W2m, xn1, hbx2, ai2, aj2, ht2h, s1i, s1j);
  k_agg2<<<NN / 16, 256, 0, stream>>>(rowptr, col, ht2h, s1i, s1j, out);
}